// Round 9
// baseline (197.052 us; speedup 1.0000x reference)
//
#include <hip/hip_runtime.h>

// Attention S=8192 D=256, scale=1/sqrt(8192)(seq len). Round 9: NO-LDS attn.
//  - Drop LDS/barriers/staging entirely: K,V stream from L1/L2. One 512-thr
//    block per CU (8 waves, M_wave=32, all same split) -> all waves read the
//    SAME 24KB/iter K+V tiles -> L1 (32KB/CU) working set; split (3MB) pins
//    to one XCD L2 via sp=bx&7.
//  - K8f frag-major layout: kf = 8 fully-coalesced 1KB b128 loads/iter.
//    Vt (pi-permuted, R7) already coalesces to 1KB per vf b128.
//  - R8 lesson: need >=2 waves/SIMD; M_wave=32 is the register ceiling.
//  - unchanged: fp8 S^T QK (A=K,B=Q), scores ARE the PV A-frag via the
//    pi-permuted Vt, f16 PV, NSPLIT=8, fp16 partials, combine epsilon.

typedef __attribute__((ext_vector_type(4))) float    f32x4;
typedef __attribute__((ext_vector_type(4))) int      i32x4;
typedef __attribute__((ext_vector_type(4))) _Float16 h4;
typedef __attribute__((ext_vector_type(8))) _Float16 h8;
typedef long __attribute__((may_alias)) long_a;
typedef i32x4 __attribute__((may_alias)) i32x4_a;
typedef h8    __attribute__((may_alias)) h8_a;

#define SEQ 8192
#define DIM 256
#define NSPLIT 8
#define KPS (SEQ / NSPLIT)          // 1024 keys per split
#define BN 32                        // keys per iteration
#define ITERS (KPS / BN)             // 32
#define BM 256                       // q rows per block = 8 waves x 32

#define KSC (1.4426950408889634f / 90.50966799187808f)   // log2(e)/sqrt(8192)

// ---- fused prep ----------------------------------------------------------
// Q8: fp8 row-major. K8f: fp8 frag-major K8f[tile32][sub16][spair][lane][16B]
// where lane=qq*16+l15 holds cols {2sp*32+qq*8..+7 | (2sp+1)*32+qq*8..+7} of
// key row sub*16+l15. Vt: f16 pi-permuted tile-transpose (R7).
__global__ void __launch_bounds__(256)
prep(const float* __restrict__ Q, const float* __restrict__ K,
     const float* __restrict__ V, unsigned char* __restrict__ Q8,
     unsigned char* __restrict__ K8f, _Float16* __restrict__ Vt) {
    __shared__ _Float16 tile[32][264];
    int b = blockIdx.x, t = threadIdx.x;

    // Q/K -> fp8 (HW RNE): thread t handles key row b*32+(t>>3), s-chunk t&7
    {
        int row = b * 32 + (t >> 3);
        int s = t & 7;
        const f32x4* q4 = (const f32x4*)Q + (size_t)row * 64 + s * 8;
        const f32x4* k4 = (const f32x4*)K + (size_t)row * 64 + s * 8;
        int qo[8], ko[8];
        #pragma unroll
        for (int i = 0; i < 8; ++i) {
            f32x4 q = q4[i], k = k4[i];
            int dq = 0, dk = 0;
            dq = __builtin_amdgcn_cvt_pk_fp8_f32(q.x, q.y, dq, false);
            dq = __builtin_amdgcn_cvt_pk_fp8_f32(q.z, q.w, dq, true);
            dk = __builtin_amdgcn_cvt_pk_fp8_f32(k.x, k.y, dk, false);
            dk = __builtin_amdgcn_cvt_pk_fp8_f32(k.z, k.w, dk, true);
            qo[i] = dq; ko[i] = dk;
        }
        i32x4* qd = (i32x4*)(Q8 + (size_t)row * 256 + s * 32);
        qd[0] = *(i32x4*)&qo[0]; qd[1] = *(i32x4*)&qo[4];

        int kk = row & 31, sub = kk >> 4, l = kk & 15;
        unsigned char* kb = K8f + (size_t)b * 8192 + sub * 4096
                          + (s >> 1) * 1024 + (s & 1) * 8;
        #pragma unroll
        for (int q2 = 0; q2 < 4; ++q2)
            *(long_a*)(kb + (q2 * 16 + l) * 16) = ((long*)ko)[q2];
    }

    // V tile b -> Vt[b][d][k_logical], f16, pi(8a+j)=4a+j / 16+4a+j-4
    #pragma unroll
    for (int i = 0; i < 8; ++i) {
        int c = t + i * 256;
        int row = c >> 6, col = c & 63;
        f32x4 v = ((const f32x4*)V)[(size_t)(b * 32 + row) * 64 + col];
        tile[row][col * 4 + 0] = (_Float16)v.x;
        tile[row][col * 4 + 1] = (_Float16)v.y;
        tile[row][col * 4 + 2] = (_Float16)v.z;
        tile[row][col * 4 + 3] = (_Float16)v.w;
    }
    __syncthreads();
    _Float16* dst = Vt + (size_t)b * 8192 + t * 32;
    #pragma unroll
    for (int a = 0; a < 4; ++a) {
        h8 w;
        #pragma unroll
        for (int j = 0; j < 4; ++j) {
            w[j]     = tile[4 * a + j][t];
            w[4 + j] = tile[16 + 4 * a + j][t];
        }
        *(h8*)(dst + a * 8) = w;
    }
}

// ---------------- main attention kernel ----------------------------------
// grid = 32 q-tiles x 8 splits = 256 blocks (1/CU), 512 threads (8 waves),
// 32 q-rows per wave. No LDS, no barriers.
__global__ void __launch_bounds__(512, 2)
attn(const unsigned char* __restrict__ Q8, const unsigned char* __restrict__ K8f,
     const _Float16* __restrict__ Vt, _Float16* __restrict__ Op,
     float* __restrict__ lp) {
    int tid = threadIdx.x;
    int wid = tid >> 6, lane = tid & 63;
    int l15 = lane & 15, qq = lane >> 4;
    int qt_blk = blockIdx.x >> 3, sp = blockIdx.x & 7;
    int qrow0 = qt_blk * BM + wid * 32;

    // Q fp8 B-frags (S^T: B[n=q=l15][k=s*32+qq*8+j]), loaded once
    long qf[2][8];
    #pragma unroll
    for (int t = 0; t < 2; ++t) {
        const unsigned char* p = Q8 + (size_t)(qrow0 + t * 16 + l15) * DIM + qq * 8;
        #pragma unroll
        for (int s = 0; s < 8; ++s) qf[t][s] = *(const long_a*)(p + s * 32);
    }

    // ones B-frag (f16, K=32) for l = P @ ones
    _Float16 one = (l15 == 0) ? (_Float16)1.0f : (_Float16)0.0f;
    h8 of = {one, one, one, one, one, one, one, one};

    // streaming bases (per-lane)
    const unsigned char* kbase = K8f + (size_t)(sp * (KPS / BN)) * 8192 + lane * 16;
    const _Float16*      vbase = Vt  + (size_t)(sp * (KPS / BN)) * 4096 * 2
                               + l15 * 32 + qq * 8;

    f32x4 acc[2][16] = {};
    f32x4 accl[2] = {};

    for (int it = 0; it < ITERS; ++it) {
        // kf: 8 coalesced b128 (1KB each) from L1/L2
        const unsigned char* kt = kbase + it * 8192;
        union { i32x4 v; long l[2]; } kfr[2][4];
        #pragma unroll
        for (int sub = 0; sub < 2; ++sub)
            #pragma unroll
            for (int p = 0; p < 4; ++p)
                kfr[sub][p].v = *(const i32x4_a*)(kt + sub * 4096 + p * 1024);

        // S^T = K @ Q^T : fp8 16x16x32
        f32x4 sc[2][2] = {};
        #pragma unroll
        for (int s = 0; s < 8; ++s) {
            long kf0 = kfr[0][s >> 1].l[s & 1];
            long kf1 = kfr[1][s >> 1].l[s & 1];
            #pragma unroll
            for (int t = 0; t < 2; ++t) {
                sc[0][t] = __builtin_amdgcn_mfma_f32_16x16x32_fp8_fp8(kf0, qf[t][s], sc[0][t], 0, 0, 0);
                sc[1][t] = __builtin_amdgcn_mfma_f32_16x16x32_fp8_fp8(kf1, qf[t][s], sc[1][t], 0, 0, 0);
            }
        }

        // P = exp2(S*KSC): [sc0|sc1] IS the K=32 PV A-frag (pi-permuted Vt)
        h8 pfrag[2];
        #pragma unroll
        for (int t = 0; t < 2; ++t)
            #pragma unroll
            for (int r = 0; r < 4; ++r) {
                pfrag[t][r]     = (_Float16)__builtin_amdgcn_exp2f(sc[0][t][r] * KSC);
                pfrag[t][4 + r] = (_Float16)__builtin_amdgcn_exp2f(sc[1][t][r] * KSC);
            }

        // O += P @ V : f16 16x16x32; vf = coalesced b128 (1KB/instr) from L1
        const _Float16* vt = vbase + it * 8192;
        #pragma unroll
        for (int n = 0; n < 16; ++n) {
            h8 vf = *(const h8_a*)(vt + n * 512);
            acc[0][n] = __builtin_amdgcn_mfma_f32_16x16x32_f16(pfrag[0], vf, acc[0][n], 0, 0, 0);
            acc[1][n] = __builtin_amdgcn_mfma_f32_16x16x32_f16(pfrag[1], vf, acc[1][n], 0, 0, 0);
        }
        accl[0] = __builtin_amdgcn_mfma_f32_16x16x32_f16(pfrag[0], of, accl[0], 0, 0, 0);
        accl[1] = __builtin_amdgcn_mfma_f32_16x16x32_f16(pfrag[1], of, accl[1], 0, 0, 0);
    }

    // epilogue: f16 O partials + fp32 l partials
    #pragma unroll
    for (int t = 0; t < 2; ++t) {
        #pragma unroll
        for (int n = 0; n < 16; ++n)
            #pragma unroll
            for (int r = 0; r < 4; ++r) {
                int row = qrow0 + t * 16 + qq * 4 + r;
                Op[((size_t)sp * SEQ + row) * DIM + n * 16 + l15] = (_Float16)acc[t][n][r];
            }
        if (l15 == 0) {
            #pragma unroll
            for (int r = 0; r < 4; ++r)
                lp[(size_t)sp * SEQ + qrow0 + t * 16 + qq * 4 + r] = accl[t][r];
        }
    }
}

// ---------------- combine: out = sum_s(Op_s) / sum_s(lp_s) ----------------
__global__ void combine(const _Float16* __restrict__ Op, const float* __restrict__ lp,
                        float* __restrict__ out) {
    int idx = blockIdx.x * 256 + threadIdx.x;   // f32x4 chunk, 524288 total
    int row = idx >> 6;
    f32x4 a = {};
    float l = 0.0f;
    #pragma unroll
    for (int s = 0; s < NSPLIT; ++s) {
        h4 h = *(const h4*)(Op + (size_t)s * SEQ * DIM + (size_t)idx * 4);
        a.x += (float)h.x; a.y += (float)h.y; a.z += (float)h.z; a.w += (float)h.w;
        l += lp[s * SEQ + row];
    }
    float linv = 1.0f / (l + 1e-20f);
    ((f32x4*)out)[idx] = a * linv;
}

extern "C" void kernel_launch(void* const* d_in, const int* in_sizes, int n_in,
                              void* d_out, int out_size, void* d_ws, size_t ws_size,
                              hipStream_t stream) {
    const float* Q = (const float*)d_in[0];
    const float* K = (const float*)d_in[1];
    const float* V = (const float*)d_in[2];
    float* out = (float*)d_out;

    char* ws = (char*)d_ws;
    unsigned char* Q8  = (unsigned char*)ws;               // 2 MB fp8
    unsigned char* K8f = (unsigned char*)(ws + (2u << 20));// 2 MB fp8 frag-major
    _Float16* Vt = (_Float16*)(ws + (4u << 20));           // 4 MB f16 tiled-T (pi)
    _Float16* Op = (_Float16*)(ws + (8u << 20));           // 32 MB f16 partials
    float*    lp = (float*)(ws + (40u << 20));             // 256 KB

    prep   <<<256, 256, 0, stream>>>(Q, K, V, Q8, K8f, Vt);
    attn   <<<NSPLIT * (SEQ / BM), 512, 0, stream>>>(Q8, K8f, Vt, Op, lp);
    combine<<<2048, 256, 0, stream>>>(Op, lp, out);
}